// Round 8
// baseline (166.124 us; speedup 1.0000x reference)
//
#include <hip/hip_runtime.h>
#include <math.h>

#define D 256              // feature dim
#define BLOCKS 2048
#define WPB 4              // waves per 256-thread block
#define GPW 4              // 2-node groups per wave: 2048*4*4*2 = 65536 nodes

// Native vector type (16B, single load instruction even when volatile).
using f32x4 = __attribute__((ext_vector_type(4))) float;

// softplus(-p) = max(-p,0) + log(1+exp(-|p|)); fast intrinsics fine:
// threshold is 135 absolute on a ~6752 output (2%).
__device__ __forceinline__ float spn(float p) {
    return fmaxf(-p, 0.0f) + __logf(1.0f + __expf(-fabsf(p)));
}

__device__ __forceinline__ float dot4(f32x4 a, f32x4 b) {
    return a.x * b.x + a.y * b.y + a.z * b.z + a.w * b.w;
}

// R8 probe: volatile 16B load -> emitted with device/system-scope cache bits
// (sc0 sc1 on gfx950): the z stream bypasses L1/L2 allocation and reads at
// the IF/L3 coherence point. Discriminates "L2 miss-tracking caps reads at
// ~3.2 TB/s" (big win) from "XCD<->IF fabric ingress cap" (exactly neutral).
// Semantically safe: inputs are read-only and written before launch; the
// compiler still manages waitcnts (inline-asm loads would corrupt its vmcnt
// accounting for the interleaved g-loads).
__device__ __forceinline__ f32x4 volload(const f32x4* p) {
    return *(const volatile f32x4*)p;
}

template<int CTRL, int ROWMASK>
__device__ __forceinline__ float dpp_add(float x) {
    int t = __builtin_amdgcn_update_dpp(0, __builtin_bit_cast(int, x), CTRL, ROWMASK, 0xf, true);
    return x + __builtin_bit_cast(float, t);
}

// 32-lane reduce: lane 31 holds sum of lanes 0..31, lane 63 of 32..63.
__device__ __forceinline__ float red32(float x) {
    x = dpp_add<0x111, 0xf>(x);   // row_shr:1
    x = dpp_add<0x112, 0xf>(x);   // row_shr:2
    x = dpp_add<0x114, 0xf>(x);   // row_shr:4
    x = dpp_add<0x118, 0xf>(x);   // row_shr:8
    x = dpp_add<0x142, 0xa>(x);   // row_bcast15
    return x;
}

// Full 64-lane reduce (result in lane 63).
__device__ __forceinline__ float red64(float x) {
    x = red32(x);
    x = dpp_add<0x143, 0xc>(x);   // row_bcast31
    return x;
}

struct ZR { f32x4 a1lo, a1hi, a2lo, a2hi; };   // this lane's z slices (16 VGPR)

// R0-R7 ledger: MLP (proven 12 via global_load_lds), traffic (384->150 MB),
// occupancy (25-64%), VALU chain (VALUBusy 30->16%) all falsified as
// limiters. Effective read rate invariant ~3.1 TB/s across all; writes do
// 6.6 TB/s (fills). R7's nt-loads broke the invariant for the first time
// (slowest dot dispatch dropped below the 40.2us fills). This round: L2
// bypass via volatile z loads, otherwise identical structure.
__global__ __launch_bounds__(256) void jsd_dot_vol_kernel(
    const int*   __restrict__ b1,
    const int*   __restrict__ b2,
    const float* __restrict__ z1,
    const float* __restrict__ z2,
    const float* __restrict__ g1,
    const float* __restrict__ g2,
    float*       __restrict__ partials)   // [BLOCKS*2]
{
    const int wave = threadIdx.x >> 6;
    const int lane = threadIdx.x & 63;
    const int sub  = lane >> 5;          // which node of the 2-node group
    const int fl   = lane & 31;          // feature lane: floats [fl*8, fl*8+8)
    const bool tail = (fl == 31);        // lanes 31, 63 hold the node sums

    const int w    = blockIdx.x * WPB + wave;
    const int base = w * (GPW * 2);      // first node of this wave's strip

    const float* z1p = z1 + (size_t)(base + sub) * D + fl * 8;
    const float* z2p = z2 + (size_t)(base + sub) * D + fl * 8;

    ZR  zr[2];
    int i1v[2], i2v[2];

    // preload group 0 (L2-bypassing stream loads)
    zr[0].a1lo = volload((const f32x4*)z1p + 0);
    zr[0].a1hi = volload((const f32x4*)z1p + 1);
    zr[0].a2lo = volload((const f32x4*)z2p + 0);
    zr[0].a2hi = volload((const f32x4*)z2p + 1);
    i1v[0] = b1[base + sub];
    i2v[0] = b2[base + sub];

    // g-row register cache (per-lane 8 floats of each of the 4 rows);
    // g loads stay NORMAL (cache-resident, reused across the strip).
    f32x4 w11lo{}, w11hi{}, w12lo{}, w12hi{};
    f32x4 w21lo{}, w21hi{}, w22lo{}, w22hi{};
    int ci1 = -1, ci2 = -1;

    float acc1 = 0.0f, acc2 = 0.0f;

    #pragma unroll
    for (int g = 0; g < GPW; ++g) {
        const int cur = g & 1;           // constant after unroll (rule #20)
        const int nxt = cur ^ 1;

        // prefetch next group's z slices + indices (in flight under compute;
        // volatile preserves program order, so these still issue early)
        if (g + 1 < GPW) {
            const float* p1 = z1p + (size_t)(g + 1) * 2 * D;
            const float* p2 = z2p + (size_t)(g + 1) * 2 * D;
            zr[nxt].a1lo = volload((const f32x4*)p1 + 0);
            zr[nxt].a1hi = volload((const f32x4*)p1 + 1);
            zr[nxt].a2lo = volload((const f32x4*)p2 + 0);
            zr[nxt].a2hi = volload((const f32x4*)p2 + 1);
            i1v[nxt] = b1[base + (g + 1) * 2 + sub];
            i2v[nxt] = b2[base + (g + 1) * 2 + sub];
        }

        const int i1 = i1v[cur];
        const int i2 = i2v[cur];

        // Reload g rows only when some lane's index changed (wave-uniform
        // branch; rare on sorted data, correct for any data).
        if (__any(i1 != ci1)) {
            const float* q = g1 + (size_t)i1 * D + fl * 8;
            const float* r = g2 + (size_t)i1 * D + fl * 8;
            w11lo = ((const f32x4*)q)[0]; w11hi = ((const f32x4*)q)[1];
            w12lo = ((const f32x4*)r)[0]; w12hi = ((const f32x4*)r)[1];
            ci1 = i1;
        }
        if (__any(i2 != ci2)) {
            const float* q = g2 + (size_t)i2 * D + fl * 8;
            const float* r = g1 + (size_t)i2 * D + fl * 8;
            w22lo = ((const f32x4*)q)[0]; w22hi = ((const f32x4*)q)[1];
            w21lo = ((const f32x4*)r)[0]; w21hi = ((const f32x4*)r)[1];
            ci2 = i2;
        }

        // 2 nodes per wave-instruction; 4 independent 5-step DPP chains.
        float p11 = dot4(zr[cur].a1lo, w11lo) + dot4(zr[cur].a1hi, w11hi);
        float p12 = dot4(zr[cur].a1lo, w12lo) + dot4(zr[cur].a1hi, w12hi);
        float p22 = dot4(zr[cur].a2lo, w22lo) + dot4(zr[cur].a2hi, w22hi);
        float p21 = dot4(zr[cur].a2lo, w21lo) + dot4(zr[cur].a2hi, w21hi);

        float s11 = red32(p11);
        float c12 = red32(p12);
        float s22 = red32(p22);
        float c21 = red32(p21);

        if (tail) {   // lanes 31,63: each finishes its own node
            float d1 = spn(c12) - spn(s11);   // f(s)-f(c) = softplus(-c)-softplus(-s)
            float d2 = spn(c21) - spn(s22);
            acc1 += d1 * d1;
            acc2 += d2 * d2;
        }
    }

    // acc lives on lanes 31,63 (0 elsewhere) -> full-wave sum to lane 63.
    acc1 = red64(acc1);
    acc2 = red64(acc2);

    __shared__ float s1[WPB], s2[WPB];
    if (lane == 63) { s1[wave] = acc1; s2[wave] = acc2; }
    __syncthreads();

    if (threadIdx.x == 0) {
        float t1 = 0.0f, t2 = 0.0f;
        #pragma unroll
        for (int k = 0; k < WPB; ++k) { t1 += s1[k]; t2 += s2[k]; }
        partials[blockIdx.x * 2 + 0] = t1;
        partials[blockIdx.x * 2 + 1] = t2;
    }
}

__global__ __launch_bounds__(256) void jsd_reduce_kernel(
    const float* __restrict__ partials,
    float*       __restrict__ out)
{
    const int tid  = threadIdx.x;
    const int wave = tid >> 6;
    const int lane = tid & 63;

    float a = 0.0f, b = 0.0f;
    #pragma unroll
    for (int i = 0; i < BLOCKS / 256; ++i) {
        a += partials[(i * 256 + tid) * 2 + 0];
        b += partials[(i * 256 + tid) * 2 + 1];
    }

    a = red64(a);
    b = red64(b);

    __shared__ float s1[4], s2[4];
    if (lane == 63) { s1[wave] = a; s2[wave] = b; }
    __syncthreads();

    if (tid == 0) {
        float t1 = s1[0] + s1[1] + s1[2] + s1[3];
        float t2 = s2[0] + s2[1] + s2[2] + s2[3];
        out[0] = sqrtf(t1) + sqrtf(t2);
    }
}

extern "C" void kernel_launch(void* const* d_in, const int* in_sizes, int n_in,
                              void* d_out, int out_size, void* d_ws, size_t ws_size,
                              hipStream_t stream) {
    const int*   b1 = (const int*)  d_in[0];
    const int*   b2 = (const int*)  d_in[1];
    const float* z1 = (const float*)d_in[2];
    const float* z2 = (const float*)d_in[3];
    const float* g1 = (const float*)d_in[4];
    const float* g2 = (const float*)d_in[5];
    float* out      = (float*)d_out;
    float* partials = (float*)d_ws;   // BLOCKS*2 floats, fully overwritten

    jsd_dot_vol_kernel<<<BLOCKS, 256, 0, stream>>>(b1, b2, z1, z2, g1, g2, partials);
    jsd_reduce_kernel<<<1, 256, 0, stream>>>(partials, out);
}